// Round 5
// baseline (186.655 us; speedup 1.0000x reference)
//
#include <hip/hip_runtime.h>
#include <math.h>

typedef __attribute__((ext_vector_type(8))) short short8;
typedef __attribute__((ext_vector_type(4))) float f32x4;

#define NB 4
#define NH 16
#define SL 1024
#define DH 64
#define BQ 64      // q rows per block (4 waves x 16)
#define WQ 16      // q rows per wave
#define KTL 64     // k rows per tile
#define NT 256
#define NKT (SL / KTL)

#define TILE_SH (KTL * DH)              // 4096 shorts = 8 KB per tile blob
#define HEAD_SH (SL * DH)               // 65536 shorts per head
#define BLOB_SH ((size_t)NB * NH * HEAD_SH)   // 8 MB per blob

// 0.125 * log2(e): scores computed directly in log2 domain
#define QSCALE 0.18033688011111543f

#if __has_builtin(__builtin_amdgcn_exp2f)
#define EXP2F(x) __builtin_amdgcn_exp2f(x)
#else
#define EXP2F(x) exp2f(x)
#endif

__device__ __forceinline__ unsigned short bf_rne(float x) {
    unsigned int u = __float_as_uint(x);
    u += 0x7fffu + ((u >> 16) & 1u);
    return (unsigned short)(u >> 16);
}
__device__ __forceinline__ void bf_split(float x, unsigned short& h, unsigned short& l) {
    unsigned int u = __float_as_uint(x);
    h = (unsigned short)(u >> 16);                       // truncate
    float r = x - __uint_as_float(u & 0xffff0000u);      // exact residual
    l = bf_rne(r);
}

typedef const __attribute__((address_space(1))) unsigned int guint_t;
typedef __attribute__((address_space(3))) unsigned int luint_t;
__device__ __forceinline__ void gload_lds16(const void* g, void* l) {
    __builtin_amdgcn_global_load_lds((guint_t*)g, (luint_t*)l, 16, 0, 0);
}

#define MFMA(a, b, c) __builtin_amdgcn_mfma_f32_16x16x32_bf16(a, b, c, 0, 0, 0)

#define WAITVM(N) do { asm volatile("s_waitcnt vmcnt(" #N ")" ::: "memory"); \
                       __builtin_amdgcn_sched_barrier(0); } while (0)
#define BAR() do { __builtin_amdgcn_sched_barrier(0); __builtin_amdgcn_s_barrier(); \
                   __builtin_amdgcn_sched_barrier(0); } while (0)
#define SCHED_FENCE() __builtin_amdgcn_sched_barrier(0)

// ============================================================================
// Prep: split K -> (khi,klo) tile-linear swizzled [kr][dc ^ ((kr&7)<<3)]
//       split V^T -> (vhi,vlo) tile-linear swizzled [d][kl ^ ((d&7)<<3)]
// ============================================================================
__global__ __launch_bounds__(NT, 4) void prep_split(
    const float* __restrict__ K, const float* __restrict__ V,
    unsigned short* __restrict__ khi, unsigned short* __restrict__ klo,
    unsigned short* __restrict__ vhi, unsigned short* __restrict__ vlo)
{
    __shared__ float sV[KTL][DH + 4];

    const int t = threadIdx.x;
    const int kt = blockIdx.x, h = blockIdx.y, b = blockIdx.z;
    const size_t goff = (size_t)(b * NH + h) * SL * DH + (size_t)kt * KTL * DH;
    const size_t toff = (size_t)(b * NH + h) * HEAD_SH + (size_t)kt * TILE_SH;

    #pragma unroll
    for (int u = 0; u < 2; ++u) {
        int idx = u * NT + t;                 // 0..511
        int kr = idx >> 3, c8 = idx & 7;
        const float* src = K + goff + kr * DH + c8 * 8;
        float4 a = *(const float4*)src;
        float4 bb = *(const float4*)(src + 4);
        float vals[8] = {a.x, a.y, a.z, a.w, bb.x, bb.y, bb.z, bb.w};
        unsigned int ph[4], pl[4];
        #pragma unroll
        for (int j = 0; j < 4; ++j) {
            unsigned short h0, l0, h1, l1;
            bf_split(vals[2 * j], h0, l0);
            bf_split(vals[2 * j + 1], h1, l1);
            ph[j] = (unsigned int)h0 | ((unsigned int)h1 << 16);
            pl[j] = (unsigned int)l0 | ((unsigned int)l1 << 16);
        }
        int dsw = (c8 * 8) ^ ((kr & 7) << 3);
        *(uint4*)&khi[toff + kr * DH + dsw] = make_uint4(ph[0], ph[1], ph[2], ph[3]);
        *(uint4*)&klo[toff + kr * DH + dsw] = make_uint4(pl[0], pl[1], pl[2], pl[3]);
    }

    #pragma unroll
    for (int u = 0; u < 4; ++u) {
        int i = u * NT + t;
        float4 v = *(const float4*)(V + goff + (size_t)i * 4);
        *(float4*)&sV[i >> 4][(i & 15) * 4] = v;
    }
    __syncthreads();
    #pragma unroll
    for (int u = 0; u < 2; ++u) {
        int idx = u * NT + t;
        int d = idx & 63, k8 = idx >> 6;
        float vals[8];
        #pragma unroll
        for (int j = 0; j < 8; ++j) vals[j] = sV[k8 * 8 + j][d];
        unsigned int ph[4], pl[4];
        #pragma unroll
        for (int j = 0; j < 4; ++j) {
            unsigned short h0, l0, h1, l1;
            bf_split(vals[2 * j], h0, l0);
            bf_split(vals[2 * j + 1], h1, l1);
            ph[j] = (unsigned int)h0 | ((unsigned int)h1 << 16);
            pl[j] = (unsigned int)l0 | ((unsigned int)l1 << 16);
        }
        int ksw = (k8 * 8) ^ ((d & 7) << 3);
        *(uint4*)&vhi[toff + d * KTL + ksw] = make_uint4(ph[0], ph[1], ph[2], ph[3]);
        *(uint4*)&vlo[toff + d * KTL + ksw] = make_uint4(pl[0], pl[1], pl[2], pl[3]);
    }
}

// ============================================================================
// Main: two-pass softmax attention, MFMA split-bf16, double-buffered DMA tiles
// ============================================================================
__global__ __launch_bounds__(NT, 2) void attn_main(
    const float* __restrict__ Q, const int* __restrict__ M,
    const unsigned short* __restrict__ khi, const unsigned short* __restrict__ klo,
    const unsigned short* __restrict__ vhi, const unsigned short* __restrict__ vlo,
    float* __restrict__ O, float* __restrict__ P)
{
    __shared__ unsigned short sK[2][2][KTL][DH];   // [buf][hi/lo][kr][d]  32KB
    __shared__ unsigned short sV[2][2][DH][KTL];   // [buf][hi/lo][d][k]   32KB
    __shared__ unsigned short sPh[4][WQ][KTL];     // per-wave P hi        8KB
    __shared__ unsigned short sPl[4][WQ][KTL];     // per-wave P lo        8KB

    const int t = threadIdx.x;
    const int l = t & 63;
    const int w = __builtin_amdgcn_readfirstlane(t >> 6);
    const int lg = l >> 4, lr = l & 15;

    // XCD-aware swizzle: XCD x gets 128 consecutive nids = 8 heads' blobs (4MB, L2-fit)
    const int flat = blockIdx.x + (blockIdx.y << 4) + (blockIdx.z << 8);
    const int nid = (flat & 7) * 128 + (flat >> 3);
    const int qt = nid & 15;
    const int hh_ = (nid >> 4) & 15;
    const int b = nid >> 8;
    const int qb = qt * BQ + w * WQ;

    const size_t hoff = (size_t)(b * NH + hh_) * SL * DH;
    const size_t headsh = (size_t)(b * NH + hh_) * HEAD_SH;
    const int*   Mw = M + ((size_t)b * SL + qb) * SL;
    float*       Pw = P + ((size_t)(b * NH + hh_) * SL + qb) * SL;
    float*       Ow = O + hoff + (size_t)qb * DH;

    // ---- Q fragments (B operand of swapped QK), scale*log2e folded in ----
    short8 qhi[2], qlo[2];
    {
        const float* src0 = Q + hoff + (size_t)(qb + lr) * DH + lg * 8;
        #pragma unroll
        for (int ds = 0; ds < 2; ++ds) {
            const float* src = src0 + ds * 32;
            float4 a = *(const float4*)src;
            float4 bb = *(const float4*)(src + 4);
            float vals[8] = {a.x, a.y, a.z, a.w, bb.x, bb.y, bb.z, bb.w};
            #pragma unroll
            for (int j = 0; j < 8; ++j) {
                unsigned short hv, lv;
                bf_split(vals[j] * QSCALE, hv, lv);
                qhi[ds][j] = (short)hv;
                qlo[ds][j] = (short)lv;
            }
        }
    }

    auto stageK = [&](int bufi, int kt) {
        const char* gh = (const char*)(khi + headsh + (size_t)kt * TILE_SH);
        const char* gl = (const char*)(klo + headsh + (size_t)kt * TILE_SH);
        char* dh = (char*)&sK[bufi][0][0][0];
        char* dl = (char*)&sK[bufi][1][0][0];
        #pragma unroll
        for (int u = 0; u < 2; ++u) {
            const int c = w * 2 + u;
            gload_lds16(gh + c * 1024 + l * 16, dh + c * 1024);
            gload_lds16(gl + c * 1024 + l * 16, dl + c * 1024);
        }
    };
    auto stageV = [&](int bufi, int kt) {
        const char* gh = (const char*)(vhi + headsh + (size_t)kt * TILE_SH);
        const char* gl = (const char*)(vlo + headsh + (size_t)kt * TILE_SH);
        char* dh = (char*)&sV[bufi][0][0][0];
        char* dl = (char*)&sV[bufi][1][0][0];
        #pragma unroll
        for (int u = 0; u < 2; ++u) {
            const int c = w * 2 + u;
            gload_lds16(gh + c * 1024 + l * 16, dh + c * 1024);
            gload_lds16(gl + c * 1024 + l * 16, dl + c * 1024);
        }
    };

    // ================= Pass 1: softmax stats (pipelined K staging) =================
    stageK(0, 0);                       // 4 DMA in flight
    float m = -INFINITY, sum = 0.f;
    int cur = 0;

    for (int kt = 0; kt < NKT; ++kt) {
        const int k0 = kt * KTL;
        int4 mv[4];
        #pragma unroll
        for (int st = 0; st < 4; ++st)
            mv[st] = *(const int4*)(Mw + (size_t)lr * SL + k0 + st * 16 + lg * 4);
        SCHED_FENCE();                  // pin mask loads before next-tile DMA issue
        if (kt + 1 < NKT) { stageK(cur ^ 1, kt + 1); WAITVM(4); }
        else              { WAITVM(0); }
        BAR();                          // all waves' tile-kt DMA landed

        f32x4 acc[4];
        #pragma unroll
        for (int st = 0; st < 4; ++st) {
            const int krow = st * 16 + lr;
            const int sw = (krow & 7) << 3;
            f32x4 c = {0.f, 0.f, 0.f, 0.f};
            #pragma unroll
            for (int ds = 0; ds < 2; ++ds) {
                int dc = (ds * 32 + lg * 8) ^ sw;
                short8 ah = *(const short8*)&sK[cur][0][krow][dc];
                short8 al = *(const short8*)&sK[cur][1][krow][dc];
                c = MFMA(ah, qhi[ds], c);
                c = MFMA(ah, qlo[ds], c);
                c = MFMA(al, qhi[ds], c);
            }
            acc[st] = c;
        }
        BAR();                          // done reading sK[cur]; softmax VALU below overlaps staging

        float s[16];
        #pragma unroll
        for (int st = 0; st < 4; ++st) {
            s[st * 4 + 0] = mv[st].x ? acc[st][0] : -1e9f;
            s[st * 4 + 1] = mv[st].y ? acc[st][1] : -1e9f;
            s[st * 4 + 2] = mv[st].z ? acc[st][2] : -1e9f;
            s[st * 4 + 3] = mv[st].w ? acc[st][3] : -1e9f;
        }
        float tmax = s[0];
        #pragma unroll
        for (int j = 1; j < 16; ++j) tmax = fmaxf(tmax, s[j]);
        tmax = fmaxf(tmax, __shfl_xor(tmax, 16));
        tmax = fmaxf(tmax, __shfl_xor(tmax, 32));
        const float mn = fmaxf(m, tmax);
        float ts = 0.f;
        #pragma unroll
        for (int j = 0; j < 16; ++j) ts += EXP2F(s[j] - mn);
        ts += __shfl_xor(ts, 16);
        ts += __shfl_xor(ts, 32);
        sum = sum * EXP2F(m - mn) + ts;
        m = mn;
        cur ^= 1;
    }

    // ================= Pass 2: P + PV (pipelined K+V staging) =================
    stageK(0, 0);
    stageV(0, 0);                       // 8 DMA in flight
    const float m2 = m + __log2f(sum);  // normalization folded into exponent
    f32x4 oacc[4];
    #pragma unroll
    for (int mt = 0; mt < 4; ++mt) oacc[mt] = (f32x4){0.f, 0.f, 0.f, 0.f};
    cur = 0;

    for (int kt = 0; kt < NKT; ++kt) {
        const int k0 = kt * KTL;
        int4 mv[4];
        #pragma unroll
        for (int st = 0; st < 4; ++st)
            mv[st] = *(const int4*)(Mw + (size_t)lr * SL + k0 + st * 16 + lg * 4);
        SCHED_FENCE();
        if (kt + 1 < NKT) { stageK(cur ^ 1, kt + 1); stageV(cur ^ 1, kt + 1); WAITVM(8); }
        else              { WAITVM(0); }
        BAR();

        #pragma unroll
        for (int st = 0; st < 4; ++st) {
            const int krow = st * 16 + lr;
            const int sw = (krow & 7) << 3;
            f32x4 c = {0.f, 0.f, 0.f, 0.f};
            #pragma unroll
            for (int ds = 0; ds < 2; ++ds) {
                int dc = (ds * 32 + lg * 8) ^ sw;
                short8 ah = *(const short8*)&sK[cur][0][krow][dc];
                short8 al = *(const short8*)&sK[cur][1][krow][dc];
                c = MFMA(ah, qhi[ds], c);
                c = MFMA(ah, qlo[ds], c);
                c = MFMA(al, qhi[ds], c);
            }
            const float p0 = mv[st].x ? EXP2F(c[0] - m2) : 0.f;
            const float p1 = mv[st].y ? EXP2F(c[1] - m2) : 0.f;
            const float p2 = mv[st].z ? EXP2F(c[2] - m2) : 0.f;
            const float p3 = mv[st].w ? EXP2F(c[3] - m2) : 0.f;
            *(float4*)(Pw + (size_t)lr * SL + (k0 + st * 16 + lg * 4)) =
                make_float4(p0, p1, p2, p3);
            unsigned short hv[4], lv[4];
            bf_split(p0, hv[0], lv[0]);
            bf_split(p1, hv[1], lv[1]);
            bf_split(p2, hv[2], lv[2]);
            bf_split(p3, hv[3], lv[3]);
            int col = (st * 16 + lg * 4) ^ ((lr & 7) << 3);
            uint2 uh, ul;
            uh.x = (unsigned int)hv[0] | ((unsigned int)hv[1] << 16);
            uh.y = (unsigned int)hv[2] | ((unsigned int)hv[3] << 16);
            ul.x = (unsigned int)lv[0] | ((unsigned int)lv[1] << 16);
            ul.y = (unsigned int)lv[2] | ((unsigned int)lv[3] << 16);
            *(uint2*)&sPh[w][lr][col] = uh;
            *(uint2*)&sPl[w][lr][col] = ul;
        }

        // PV: O^T += V^T * P^T
        short8 pbh[2], pbl[2];
        #pragma unroll
        for (int ks = 0; ks < 2; ++ks) {
            int col = (ks * 32 + lg * 8) ^ ((lr & 7) << 3);
            pbh[ks] = *(const short8*)&sPh[w][lr][col];
            pbl[ks] = *(const short8*)&sPl[w][lr][col];
        }
        #pragma unroll
        for (int mt = 0; mt < 4; ++mt) {
            const int d = mt * 16 + lr;
            const int swd = (d & 7) << 3;
            #pragma unroll
            for (int ks = 0; ks < 2; ++ks) {
                int col = (ks * 32 + lg * 8) ^ swd;
                short8 vh = *(const short8*)&sV[cur][0][d][col];
                short8 vl = *(const short8*)&sV[cur][1][d][col];
                oacc[mt] = MFMA(vh, pbh[ks], oacc[mt]);
                oacc[mt] = MFMA(vh, pbl[ks], oacc[mt]);
                oacc[mt] = MFMA(vl, pbh[ks], oacc[mt]);
            }
        }
        BAR();                          // done reading sK/sV[cur]
        cur ^= 1;
    }

    #pragma unroll
    for (int mt = 0; mt < 4; ++mt) {
        float4 o = make_float4(oacc[mt][0], oacc[mt][1], oacc[mt][2], oacc[mt][3]);
        *(float4*)(Ow + (size_t)lr * DH + mt * 16 + lg * 4) = o;
    }
}

// ============================================================================
// Fallback (round-2 kernel) if workspace is too small for the blobs
// ============================================================================
__global__ __launch_bounds__(NT, 2) void attn_fallback(
    const float* __restrict__ Q, const float* __restrict__ K,
    const float* __restrict__ V, const int* __restrict__ M,
    float* __restrict__ O, float* __restrict__ P)
{
    __shared__ unsigned short sKhi[KTL][DH];
    __shared__ unsigned short sKlo[KTL][DH];
    __shared__ unsigned short sVhi[DH][KTL];
    __shared__ unsigned short sVlo[DH][KTL];
    __shared__ unsigned short sPhi[4][WQ][KTL];
    __shared__ unsigned short sPlo[4][WQ][KTL];

    const int t = threadIdx.x;
    const int l = t & 63;
    const int w = t >> 6;
    const int lg = l >> 4;
    const int lr = l & 15;

    const int hh_ = blockIdx.y, b = blockIdx.z;
    const int qb = blockIdx.x * BQ + w * WQ;

    const size_t hoff = (size_t)(b * NH + hh_) * SL * DH;
    const float* Kh = K + hoff;
    const float* Vh = V + hoff;
    const int*   Mw = M + ((size_t)b * SL + qb) * SL;
    float*       Pw = P + ((size_t)(b * NH + hh_) * SL + qb) * SL;
    float*       Ow = O + hoff + (size_t)qb * DH;

    short8 qhi[2], qlo[2];
    {
        const float* src0 = Q + hoff + (size_t)(qb + lr) * DH + lg * 8;
        #pragma unroll
        for (int ds = 0; ds < 2; ++ds) {
            const float* src = src0 + ds * 32;
            float4 a = *(const float4*)src;
            float4 bb = *(const float4*)(src + 4);
            float vals[8] = {a.x, a.y, a.z, a.w, bb.x, bb.y, bb.z, bb.w};
            #pragma unroll
            for (int j = 0; j < 8; ++j) {
                unsigned short hv, lv;
                bf_split(vals[j] * 0.125f, hv, lv);
                qhi[ds][j] = (short)hv;
                qlo[ds][j] = (short)lv;
            }
        }
    }

    auto stageK = [&](int k0) {
        #pragma unroll
        for (int u = 0; u < 2; ++u) {
            int idx = u * NT + t;
            int kr = idx >> 3;
            int dc = (idx & 7) * 8;
            const float* src = Kh + (size_t)(k0 + kr) * DH + dc;
            float4 a = *(const float4*)src;
            float4 bb = *(const float4*)(src + 4);
            float vals[8] = {a.x, a.y, a.z, a.w, bb.x, bb.y, bb.z, bb.w};
            unsigned int ph[4], pl[4];
            #pragma unroll
            for (int j = 0; j < 4; ++j) {
                unsigned short h0, l0, h1, l1;
                bf_split(vals[2 * j], h0, l0);
                bf_split(vals[2 * j + 1], h1, l1);
                ph[j] = (unsigned int)h0 | ((unsigned int)h1 << 16);
                pl[j] = (unsigned int)l0 | ((unsigned int)l1 << 16);
            }
            int dsw = dc ^ ((kr & 7) << 3);
            *(uint4*)&sKhi[kr][dsw] = make_uint4(ph[0], ph[1], ph[2], ph[3]);
            *(uint4*)&sKlo[kr][dsw] = make_uint4(pl[0], pl[1], pl[2], pl[3]);
        }
    };

    float m = -INFINITY, sum = 0.f;
    for (int kt = 0; kt < NKT; ++kt) {
        const int k0 = kt * KTL;
        __syncthreads();
        stageK(k0);
        __syncthreads();
        f32x4 acc[4];
        #pragma unroll
        for (int st = 0; st < 4; ++st) {
            const int krow = st * 16 + lr;
            const int sw = (krow & 7) << 3;
            f32x4 c = {0.f, 0.f, 0.f, 0.f};
            #pragma unroll
            for (int ds = 0; ds < 2; ++ds) {
                int dc = (ds * 32 + lg * 8) ^ sw;
                short8 ah = *(const short8*)&sKhi[krow][dc];
                short8 al = *(const short8*)&sKlo[krow][dc];
                c = MFMA(ah, qhi[ds], c);
                c = MFMA(ah, qlo[ds], c);
                c = MFMA(al, qhi[ds], c);
            }
            acc[st] = c;
        }
        float s[16];
        #pragma unroll
        for (int st = 0; st < 4; ++st) {
            const int4 mv = *(const int4*)(Mw + (size_t)lr * SL + k0 + st * 16 + lg * 4);
            s[st * 4 + 0] = mv.x ? acc[st][0] : -1e9f;
            s[st * 4 + 1] = mv.y ? acc[st][1] : -1e9f;
            s[st * 4 + 2] = mv.z ? acc[st][2] : -1e9f;
            s[st * 4 + 3] = mv.w ? acc[st][3] : -1e9f;
        }
        float tmax = s[0];
        #pragma unroll
        for (int j = 1; j < 16; ++j) tmax = fmaxf(tmax, s[j]);
        tmax = fmaxf(tmax, __shfl_xor(tmax, 16));
        tmax = fmaxf(tmax, __shfl_xor(tmax, 32));
        const float mn = fmaxf(m, tmax);
        float ts = 0.f;
        #pragma unroll
        for (int j = 0; j < 16; ++j) ts += __expf(s[j] - mn);
        ts += __shfl_xor(ts, 16);
        ts += __shfl_xor(ts, 32);
        sum = sum * __expf(m - mn) + ts;
        m = mn;
    }
    const float inv = 1.f / sum;

    f32x4 oacc[4];
    #pragma unroll
    for (int mt = 0; mt < 4; ++mt) oacc[mt] = (f32x4){0.f, 0.f, 0.f, 0.f};

    for (int kt = 0; kt < NKT; ++kt) {
        const int k0 = kt * KTL;
        __syncthreads();
        stageK(k0);
        {
            int d0 = (t & 15) * 4;
            int kl0 = (t >> 4) * 4;
            float4 r[4];
            #pragma unroll
            for (int i = 0; i < 4; ++i)
                r[i] = *(const float4*)(Vh + (size_t)(k0 + kl0 + i) * DH + d0);
            const float* rp = (const float*)r;
            #pragma unroll
            for (int j = 0; j < 4; ++j) {
                unsigned short hv[4], lv[4];
                #pragma unroll
                for (int i = 0; i < 4; ++i) bf_split(rp[i * 4 + j], hv[i], lv[i]);
                int d = d0 + j;
                int csw = kl0 ^ ((d & 7) << 3);
                uint2 uh, ul;
                uh.x = (unsigned int)hv[0] | ((unsigned int)hv[1] << 16);
                uh.y = (unsigned int)hv[2] | ((unsigned int)hv[3] << 16);
                ul.x = (unsigned int)lv[0] | ((unsigned int)lv[1] << 16);
                ul.y = (unsigned int)lv[2] | ((unsigned int)lv[3] << 16);
                *(uint2*)&sVhi[d][csw] = uh;
                *(uint2*)&sVlo[d][csw] = ul;
            }
        }
        __syncthreads();

        #pragma unroll
        for (int st = 0; st < 4; ++st) {
            const int krow = st * 16 + lr;
            const int sw = (krow & 7) << 3;
            f32x4 c = {0.f, 0.f, 0.f, 0.f};
            #pragma unroll
            for (int ds = 0; ds < 2; ++ds) {
                int dc = (ds * 32 + lg * 8) ^ sw;
                short8 ah = *(const short8*)&sKhi[krow][dc];
                short8 al = *(const short8*)&sKlo[krow][dc];
                c = MFMA(ah, qhi[ds], c);
                c = MFMA(ah, qlo[ds], c);
                c = MFMA(al, qhi[ds], c);
            }
            const int4 mv = *(const int4*)(Mw + (size_t)lr * SL + k0 + st * 16 + lg * 4);
            float p0 = mv.x ? __expf(c[0] - m) * inv : 0.f;
            float p1 = mv.y ? __expf(c[1] - m) * inv : 0.f;
            float p2 = mv.z ? __expf(c[2] - m) * inv : 0.f;
            float p3 = mv.w ? __expf(c[3] - m) * inv : 0.f;
            *(float4*)(Pw + (size_t)lr * SL + (k0 + st * 16 + lg * 4)) =
                make_float4(p0, p1, p2, p3);
            unsigned short hv[4], lv[4];
            bf_split(p0, hv[0], lv[0]);
            bf_split(p1, hv[1], lv[1]);
            bf_split(p2, hv[2], lv[2]);
            bf_split(p3, hv[3], lv[3]);
            int col = (st * 16 + lg * 4) ^ ((lr & 7) << 3);
            uint2 uh, ul;
            uh.x = (unsigned int)hv[0] | ((unsigned int)hv[1] << 16);
            uh.y = (unsigned int)hv[2] | ((unsigned int)hv[3] << 16);
            ul.x = (unsigned int)lv[0] | ((unsigned int)lv[1] << 16);
            ul.y = (unsigned int)lv[2] | ((unsigned int)lv[3] << 16);
            *(uint2*)&sPhi[w][lr][col] = uh;
            *(uint2*)&sPlo[w][lr][col] = ul;
        }

        short8 pbh[2], pbl[2];
        #pragma unroll
        for (int ks = 0; ks < 2; ++ks) {
            int col = (ks * 32 + lg * 8) ^ ((lr & 7) << 3);
            pbh[ks] = *(const short8*)&sPhi[w][lr][col];
            pbl[ks] = *(const short8*)&sPlo[w][lr][col];
        }
        #pragma unroll
        for (int mt = 0; mt < 4; ++mt) {
            const int d = mt * 16 + lr;
            const int swd = (d & 7) << 3;
            #pragma unroll
            for (int ks = 0; ks < 2; ++ks) {
                int col = (ks * 32 + lg * 8) ^ swd;
                short8 vh = *(const short8*)&sVhi[d][col];
                short8 vl = *(const short8*)&sVlo[d][col];
                oacc[mt] = MFMA(vh, pbh[ks], oacc[mt]);
                oacc[mt] = MFMA(vh, pbl[ks], oacc[mt]);
                oacc[mt] = MFMA(vl, pbh[ks], oacc[mt]);
            }
        }
    }

    #pragma unroll
    for (int mt = 0; mt < 4; ++mt) {
        float4 o = make_float4(oacc[mt][0], oacc[mt][1], oacc[mt][2], oacc[mt][3]);
        *(float4*)(Ow + (size_t)lr * DH + mt * 16 + lg * 4) = o;
    }
}

extern "C" void kernel_launch(void* const* d_in, const int* in_sizes, int n_in,
                              void* d_out, int out_size, void* d_ws, size_t ws_size,
                              hipStream_t stream) {
    const float* Q = (const float*)d_in[0];
    const float* K = (const float*)d_in[1];
    const float* V = (const float*)d_in[2];
    const int*   M = (const int*)d_in[3];
    float* O = (float*)d_out;
    float* P = O + (size_t)NB * NH * SL * DH;   // outputs: out, p_attn

    const size_t need = 4 * BLOB_SH * sizeof(unsigned short);   // 32 MB
    if (ws_size >= need) {
        unsigned short* khi = (unsigned short*)d_ws;
        unsigned short* klo = khi + BLOB_SH;
        unsigned short* vhi = klo + BLOB_SH;
        unsigned short* vlo = vhi + BLOB_SH;
        hipLaunchKernelGGL(prep_split, dim3(NKT, NH, NB), dim3(NT, 1, 1), 0, stream,
                           K, V, khi, klo, vhi, vlo);
        hipLaunchKernelGGL(attn_main, dim3(SL / BQ, NH, NB), dim3(NT, 1, 1), 0, stream,
                           Q, M, khi, klo, vhi, vlo, O, P);
    } else {
        hipLaunchKernelGGL(attn_fallback, dim3(SL / BQ, NH, NB), dim3(NT, 1, 1), 0, stream,
                           Q, K, V, M, O, P);
    }
}

// Round 6
// 156.082 us; speedup vs baseline: 1.1959x; 1.1959x over previous
//
#include <hip/hip_runtime.h>
#include <math.h>

typedef __attribute__((ext_vector_type(8))) short short8;
typedef __attribute__((ext_vector_type(4))) float f32x4;

#define NB 4
#define NH 16
#define SL 1024
#define DH 64
#define BQ 64      // q rows per block (4 waves x 16)
#define WQ 16      // q rows per wave
#define KTL 32     // k rows per tile
#define NT 256
#define NKT (SL / KTL)                  // 32 tiles

#define TILE_SH (2 * KTL * DH)          // 4096 shorts per tile (hi 2048 + lo 2048)
#define HEAD_SH ((size_t)NKT * TILE_SH) // 131072 shorts per head
#define BLOB_SH ((size_t)NB * NH * HEAD_SH)  // 16 MB per blob (shorts)
#define BMROW   (SL / 32)               // 32 dwords of mask bits per q row

// 0.125 * log2(e): scores computed directly in log2 domain
#define QSCALE 0.18033688011111543f
#define NEGB  -1.5e9f                   // masked bias; exp2 underflows to exact 0

#if __has_builtin(__builtin_amdgcn_exp2f)
#define EXP2F(x) __builtin_amdgcn_exp2f(x)
#else
#define EXP2F(x) exp2f(x)
#endif

__device__ __forceinline__ unsigned short bf_rne(float x) {
    unsigned int u = __float_as_uint(x);
    u += 0x7fffu + ((u >> 16) & 1u);
    return (unsigned short)(u >> 16);
}
__device__ __forceinline__ void bf_split(float x, unsigned short& h, unsigned short& l) {
    unsigned int u = __float_as_uint(x);
    h = (unsigned short)(u >> 16);                       // truncate
    float r = x - __uint_as_float(u & 0xffff0000u);      // exact residual
    l = bf_rne(r);
}

typedef const __attribute__((address_space(1))) unsigned int guint_t;
typedef __attribute__((address_space(3))) unsigned int luint_t;
__device__ __forceinline__ void gload_lds16(const void* g, void* l) {
    __builtin_amdgcn_global_load_lds((guint_t*)g, (luint_t*)l, 16, 0, 0);
}

#define MFMA(a, b, c) __builtin_amdgcn_mfma_f32_16x16x32_bf16(a, b, c, 0, 0, 0)

#define WAITVM(N) do { asm volatile("s_waitcnt vmcnt(" #N ")" ::: "memory"); \
                       __builtin_amdgcn_sched_barrier(0); } while (0)
#define BAR() do { __builtin_amdgcn_sched_barrier(0); __builtin_amdgcn_s_barrier(); \
                   __builtin_amdgcn_sched_barrier(0); } while (0)
#define SCHED_FENCE() __builtin_amdgcn_sched_barrier(0)

// ============================================================================
// prep_mask: pack int mask [B,1,L,L] -> bitmask [B][L][L/32] via ballot
// ============================================================================
__global__ __launch_bounds__(NT, 4) void prep_mask(
    const int* __restrict__ M, unsigned* __restrict__ bm)
{
    const size_t total = (size_t)NB * SL * SL;
    const int l = threadIdx.x & 63;
    for (size_t i = (size_t)blockIdx.x * NT + threadIdx.x; i < total;
         i += (size_t)gridDim.x * NT) {
        int v = M[i];
        unsigned long long b = __ballot(v != 0);
        if (l == 0)       bm[i >> 5] = (unsigned)b;
        else if (l == 32) bm[i >> 5] = (unsigned)(b >> 32);
    }
}

// ============================================================================
// prep_split: K -> interleaved (hi,lo) tile blob [kr][d ^ ((kr&7)<<3)]
//             V^T -> interleaved (hi,lo) tile blob [d][k ^ ((d&3)<<3)]
// Blob byte order == main kernel's LDS order -> staging is pure 16B DMA.
// ============================================================================
__global__ __launch_bounds__(NT, 4) void prep_split(
    const float* __restrict__ K, const float* __restrict__ V,
    unsigned short* __restrict__ kb, unsigned short* __restrict__ vb)
{
    __shared__ float sVs[KTL][DH + 4];

    const int t = threadIdx.x;
    const int kt = blockIdx.x, h = blockIdx.y, b = blockIdx.z;
    const size_t goff = (size_t)(b * NH + h) * SL * DH + (size_t)kt * KTL * DH;
    const size_t tks = (size_t)(b * NH + h) * HEAD_SH + (size_t)kt * TILE_SH;

    // ---- K: 32 rows x 8 chunks = 256 granules, 1/thread
    {
        int kr = t >> 3, c8 = t & 7;
        const float* src = K + goff + kr * DH + c8 * 8;
        float4 a = *(const float4*)src;
        float4 bb = *(const float4*)(src + 4);
        float vals[8] = {a.x, a.y, a.z, a.w, bb.x, bb.y, bb.z, bb.w};
        unsigned int ph[4], pl[4];
        #pragma unroll
        for (int j = 0; j < 4; ++j) {
            unsigned short h0, l0, h1, l1;
            bf_split(vals[2 * j], h0, l0);
            bf_split(vals[2 * j + 1], h1, l1);
            ph[j] = (unsigned int)h0 | ((unsigned int)h1 << 16);
            pl[j] = (unsigned int)l0 | ((unsigned int)l1 << 16);
        }
        int dsw = (c8 * 8) ^ ((kr & 7) << 3);
        *(uint4*)&kb[tks + kr * DH + dsw]           = make_uint4(ph[0], ph[1], ph[2], ph[3]);
        *(uint4*)&kb[tks + KTL * DH + kr * DH + dsw] = make_uint4(pl[0], pl[1], pl[2], pl[3]);
    }

    // ---- V: stage fp32 tile, transpose via LDS
    #pragma unroll
    for (int u = 0; u < 2; ++u) {
        int i = u * NT + t;                   // float4 id 0..511
        float4 v = *(const float4*)(V + goff + (size_t)i * 4);
        *(float4*)&sVs[i >> 4][(i & 15) * 4] = v;
    }
    __syncthreads();
    {
        int d = t >> 2, k8 = t & 3;           // 64 d x 4 kchunks = 256 granules
        float vals[8];
        #pragma unroll
        for (int j = 0; j < 8; ++j) vals[j] = sVs[k8 * 8 + j][d];
        unsigned int ph[4], pl[4];
        #pragma unroll
        for (int j = 0; j < 4; ++j) {
            unsigned short h0, l0, h1, l1;
            bf_split(vals[2 * j], h0, l0);
            bf_split(vals[2 * j + 1], h1, l1);
            ph[j] = (unsigned int)h0 | ((unsigned int)h1 << 16);
            pl[j] = (unsigned int)l0 | ((unsigned int)l1 << 16);
        }
        int ksw = (k8 * 8) ^ ((d & 3) << 3);
        *(uint4*)&vb[tks + d * KTL + ksw]            = make_uint4(ph[0], ph[1], ph[2], ph[3]);
        *(uint4*)&vb[tks + KTL * DH + d * KTL + ksw] = make_uint4(pl[0], pl[1], pl[2], pl[3]);
    }
}

// ============================================================================
// Main: two-pass softmax attention, split-bf16 MFMA, store-slack vmcnt pipeline
// LDS = 40960 B exactly -> 4 blocks/CU.
// ============================================================================
__global__ __launch_bounds__(NT, 4) void attn_main(
    const float* __restrict__ Q, const unsigned* __restrict__ bm,
    const unsigned short* __restrict__ kb, const unsigned short* __restrict__ vb,
    float* __restrict__ O, float* __restrict__ P)
{
    __shared__ unsigned short sK[2][TILE_SH];   // 16384 B (hi 2048 | lo 2048 per buf)
    __shared__ unsigned short sV[2][TILE_SH];   // 16384 B
    __shared__ unsigned short sPh[4][WQ][KTL];  // 4096 B
    __shared__ unsigned short sPl[4][WQ][KTL];  // 4096 B

    const int t = threadIdx.x;
    const int l = t & 63;
    const int w = __builtin_amdgcn_readfirstlane(t >> 6);
    const int lg = l >> 4, lr = l & 15;

    // XCD-aware swizzle: XCD x gets 128 consecutive nids (8 heads' blobs, L2-fit)
    const int flat = blockIdx.x + (blockIdx.y << 4) + (blockIdx.z << 8);
    const int nid = (flat & 7) * 128 + (flat >> 3);
    const int qt = nid & 15;
    const int hh_ = (nid >> 4) & 15;
    const int b = nid >> 8;
    const int qb = qt * BQ + w * WQ;

    const size_t hoff = (size_t)(b * NH + hh_) * SL * DH;
    const size_t headsh = (size_t)(b * NH + hh_) * HEAD_SH;
    const unsigned short* kbh = kb + headsh;
    const unsigned short* vbh = vb + headsh;
    const unsigned* bmRow = bm + ((size_t)b * SL + qb + lr) * BMROW;
    float* Pw = P + ((size_t)(b * NH + hh_) * SL + qb) * SL;
    float* Ow = O + hoff + (size_t)qb * DH;

    // ---- Q fragments (B operand of swapped QK), scale*log2e folded in ----
    short8 qhi[2], qlo[2];
    {
        const float* src0 = Q + hoff + (size_t)(qb + lr) * DH + lg * 8;
        #pragma unroll
        for (int ds = 0; ds < 2; ++ds) {
            const float* src = src0 + ds * 32;
            float4 a = *(const float4*)src;
            float4 bb = *(const float4*)(src + 4);
            float vals[8] = {a.x, a.y, a.z, a.w, bb.x, bb.y, bb.z, bb.w};
            #pragma unroll
            for (int j = 0; j < 8; ++j) {
                unsigned short hv, lv;
                bf_split(vals[j] * QSCALE, hv, lv);
                qhi[ds][j] = (short)hv;
                qlo[ds][j] = (short)lv;
            }
        }
    }

    auto stage = [&](unsigned short* lds, const unsigned short* gtile) {
        #pragma unroll
        for (int u = 0; u < 2; ++u) {
            const int c = w * 2 + u;           // 8 x 1KB chunks per tile
            gload_lds16((const char*)gtile + c * 1024 + l * 16, (char*)lds + c * 1024);
        }
    };

    // ================= Pass 1: softmax stats =================
    stage(sK[0], kbh);
    unsigned bmv = bmRow[0];
    float m = -INFINITY, sum = 0.f;
    int cur = 0;

    for (int kt = 0; kt < NKT; ++kt) {
        WAITVM(0);                     // drains stage_kt + bm_kt (nothing else live)
        BAR();                         // all waves' tile-kt DMA landed
        unsigned bmn = 0;
        if (kt + 1 < NKT) {            // prefetch next tile into other buffer
            stage(sK[cur ^ 1], kbh + (size_t)(kt + 1) * TILE_SH);
            bmn = bmRow[kt + 1];
        }
        SCHED_FENCE();                 // pin prefetch issue before everything below

        f32x4 acc[2];
        #pragma unroll
        for (int st = 0; st < 2; ++st) {
            const int krow = st * 16 + lr;
            const int sw = (krow & 7) << 3;
            f32x4 c = {0.f, 0.f, 0.f, 0.f};
            #pragma unroll
            for (int ds = 0; ds < 2; ++ds) {
                int dc = (ds * 32 + lg * 8) ^ sw;
                short8 ah = *(const short8*)&sK[cur][krow * DH + dc];
                short8 al = *(const short8*)&sK[cur][KTL * DH + krow * DH + dc];
                c = MFMA(ah, qhi[ds], c);
                c = MFMA(ah, qlo[ds], c);
                c = MFMA(al, qhi[ds], c);
            }
            acc[st] = c;
        }

        float s[8];
        #pragma unroll
        for (int st = 0; st < 2; ++st)
            #pragma unroll
            for (int j = 0; j < 4; ++j) {
                unsigned bit = (bmv >> (st * 16 + lg * 4 + j)) & 1u;
                s[st * 4 + j] = acc[st][j] + (bit ? 0.f : NEGB);
            }
        float tmax = s[0];
        #pragma unroll
        for (int j = 1; j < 8; ++j) tmax = fmaxf(tmax, s[j]);
        tmax = fmaxf(tmax, __shfl_xor(tmax, 16));
        tmax = fmaxf(tmax, __shfl_xor(tmax, 32));
        const float mn = fmaxf(m, tmax);
        float ts = 0.f;
        #pragma unroll
        for (int j = 0; j < 8; ++j) ts += EXP2F(s[j] - mn);
        ts += __shfl_xor(ts, 16);
        ts += __shfl_xor(ts, 32);
        sum = sum * EXP2F(m - mn) + ts;
        m = mn;
        bmv = bmn;
        cur ^= 1;
    }

    // ================= Pass 2: P + PV =================
    stage(sK[0], kbh);
    stage(sV[0], vbh);
    bmv = bmRow[0];
    const float m2 = m + __log2f(sum);  // normalization folded into exponent
    f32x4 oacc[4];
    #pragma unroll
    for (int mt = 0; mt < 4; ++mt) oacc[mt] = (f32x4){0.f, 0.f, 0.f, 0.f};
    cur = 0;

    for (int kt = 0; kt < NKT; ++kt) {
        const int k0 = kt * KTL;
        // Steady state outstanding (issue order): stage_kt(4), bm_kt(1), Pstores_{kt-1}(2)
        // WAITVM(2) drains stage+bm, leaves the stores in flight (a full tile of slack).
        if (kt == 0) { WAITVM(0); } else { WAITVM(2); }
        BAR();
        unsigned bmn = 0;
        if (kt + 1 < NKT) {
            stage(sK[cur ^ 1], kbh + (size_t)(kt + 1) * TILE_SH);
            stage(sV[cur ^ 1], vbh + (size_t)(kt + 1) * TILE_SH);
            bmn = bmRow[kt + 1];
        }
        SCHED_FENCE();                 // stores below must not reorder above this

        f32x4 acc[2];
        #pragma unroll
        for (int st = 0; st < 2; ++st) {
            const int krow = st * 16 + lr;
            const int sw = (krow & 7) << 3;
            f32x4 c = {0.f, 0.f, 0.f, 0.f};
            #pragma unroll
            for (int ds = 0; ds < 2; ++ds) {
                int dc = (ds * 32 + lg * 8) ^ sw;
                short8 ah = *(const short8*)&sK[cur][krow * DH + dc];
                short8 al = *(const short8*)&sK[cur][KTL * DH + krow * DH + dc];
                c = MFMA(ah, qhi[ds], c);
                c = MFMA(ah, qlo[ds], c);
                c = MFMA(al, qhi[ds], c);
            }
            acc[st] = c;
        }

        #pragma unroll
        for (int st = 0; st < 2; ++st) {
            float p[4];
            #pragma unroll
            for (int j = 0; j < 4; ++j) {
                unsigned bit = (bmv >> (st * 16 + lg * 4 + j)) & 1u;
                float sj = acc[st][j] + (bit ? 0.f : NEGB);
                p[j] = EXP2F(sj - m2);         // masked -> exp2(-1.5e9) == exact 0
            }
            *(float4*)(Pw + (size_t)lr * SL + (k0 + st * 16 + lg * 4)) =
                make_float4(p[0], p[1], p[2], p[3]);
            unsigned short hv[4], lv[4];
            #pragma unroll
            for (int j = 0; j < 4; ++j) bf_split(p[j], hv[j], lv[j]);
            int col = (st * 16 + lg * 4) ^ ((lr & 3) << 3);
            uint2 uh, ul;
            uh.x = (unsigned int)hv[0] | ((unsigned int)hv[1] << 16);
            uh.y = (unsigned int)hv[2] | ((unsigned int)hv[3] << 16);
            ul.x = (unsigned int)lv[0] | ((unsigned int)lv[1] << 16);
            ul.y = (unsigned int)lv[2] | ((unsigned int)lv[3] << 16);
            *(uint2*)&sPh[w][lr][col] = uh;
            *(uint2*)&sPl[w][lr][col] = ul;
        }

        // PV: O^T += V^T * P^T  (per-wave sP, compiler inserts lgkm waits)
        const int pcol = (lg * 8) ^ ((lr & 3) << 3);
        short8 pbh = *(const short8*)&sPh[w][lr][pcol];
        short8 pbl = *(const short8*)&sPl[w][lr][pcol];
        #pragma unroll
        for (int mt = 0; mt < 4; ++mt) {
            const int d = mt * 16 + lr;
            const int col = (lg * 8) ^ ((d & 3) << 3);
            short8 vh = *(const short8*)&sV[cur][d * KTL + col];
            short8 vl = *(const short8*)&sV[cur][KTL * DH + d * KTL + col];
            oacc[mt] = MFMA(vh, pbh, oacc[mt]);
            oacc[mt] = MFMA(vh, pbl, oacc[mt]);
            oacc[mt] = MFMA(vl, pbh, oacc[mt]);
        }
        bmv = bmn;
        cur ^= 1;
    }

    #pragma unroll
    for (int mt = 0; mt < 4; ++mt) {
        float4 o = make_float4(oacc[mt][0], oacc[mt][1], oacc[mt][2], oacc[mt][3]);
        *(float4*)(Ow + (size_t)lr * DH + mt * 16 + lg * 4) = o;
    }
}

// ============================================================================
// Fallback (verified round-2 kernel) if workspace is too small
// ============================================================================
__global__ __launch_bounds__(NT, 2) void attn_fallback(
    const float* __restrict__ Q, const float* __restrict__ K,
    const float* __restrict__ V, const int* __restrict__ M,
    float* __restrict__ O, float* __restrict__ P)
{
    __shared__ unsigned short sKhi[64][DH];
    __shared__ unsigned short sKlo[64][DH];
    __shared__ unsigned short sVhi[DH][64];
    __shared__ unsigned short sVlo[DH][64];
    __shared__ unsigned short sPhi[4][WQ][64];
    __shared__ unsigned short sPlo[4][WQ][64];

    const int t = threadIdx.x;
    const int l = t & 63;
    const int w = t >> 6;
    const int lg = l >> 4;
    const int lr = l & 15;

    const int hh_ = blockIdx.y, b = blockIdx.z;
    const int qb = blockIdx.x * BQ + w * WQ;

    const size_t hoff = (size_t)(b * NH + hh_) * SL * DH;
    const float* Kh = K + hoff;
    const float* Vh = V + hoff;
    const int*   Mw = M + ((size_t)b * SL + qb) * SL;
    float*       Pw = P + ((size_t)(b * NH + hh_) * SL + qb) * SL;
    float*       Ow = O + hoff + (size_t)qb * DH;

    short8 qhi[2], qlo[2];
    {
        const float* src0 = Q + hoff + (size_t)(qb + lr) * DH + lg * 8;
        #pragma unroll
        for (int ds = 0; ds < 2; ++ds) {
            const float* src = src0 + ds * 32;
            float4 a = *(const float4*)src;
            float4 bb = *(const float4*)(src + 4);
            float vals[8] = {a.x, a.y, a.z, a.w, bb.x, bb.y, bb.z, bb.w};
            #pragma unroll
            for (int j = 0; j < 8; ++j) {
                unsigned short hv, lv;
                bf_split(vals[j] * 0.125f, hv, lv);
                qhi[ds][j] = (short)hv;
                qlo[ds][j] = (short)lv;
            }
        }
    }

    auto stageK = [&](int k0) {
        #pragma unroll
        for (int u = 0; u < 2; ++u) {
            int idx = u * NT + t;
            int kr = idx >> 3;
            int dc = (idx & 7) * 8;
            const float* src = Kh + (size_t)(k0 + kr) * DH + dc;
            float4 a = *(const float4*)src;
            float4 bb = *(const float4*)(src + 4);
            float vals[8] = {a.x, a.y, a.z, a.w, bb.x, bb.y, bb.z, bb.w};
            unsigned int ph[4], pl[4];
            #pragma unroll
            for (int j = 0; j < 4; ++j) {
                unsigned short h0, l0, h1, l1;
                bf_split(vals[2 * j], h0, l0);
                bf_split(vals[2 * j + 1], h1, l1);
                ph[j] = (unsigned int)h0 | ((unsigned int)h1 << 16);
                pl[j] = (unsigned int)l0 | ((unsigned int)l1 << 16);
            }
            int dsw = dc ^ ((kr & 7) << 3);
            *(uint4*)&sKhi[kr][dsw] = make_uint4(ph[0], ph[1], ph[2], ph[3]);
            *(uint4*)&sKlo[kr][dsw] = make_uint4(pl[0], pl[1], pl[2], pl[3]);
        }
    };

    float m = -INFINITY, sum = 0.f;
    for (int kt = 0; kt < 16; ++kt) {
        const int k0 = kt * 64;
        __syncthreads();
        stageK(k0);
        __syncthreads();
        f32x4 acc[4];
        #pragma unroll
        for (int st = 0; st < 4; ++st) {
            const int krow = st * 16 + lr;
            const int sw = (krow & 7) << 3;
            f32x4 c = {0.f, 0.f, 0.f, 0.f};
            #pragma unroll
            for (int ds = 0; ds < 2; ++ds) {
                int dc = (ds * 32 + lg * 8) ^ sw;
                short8 ah = *(const short8*)&sKhi[krow][dc];
                short8 al = *(const short8*)&sKlo[krow][dc];
                c = MFMA(ah, qhi[ds], c);
                c = MFMA(ah, qlo[ds], c);
                c = MFMA(al, qhi[ds], c);
            }
            acc[st] = c;
        }
        float s[16];
        #pragma unroll
        for (int st = 0; st < 4; ++st) {
            const int4 mv = *(const int4*)(Mw + (size_t)lr * SL + k0 + st * 16 + lg * 4);
            s[st * 4 + 0] = mv.x ? acc[st][0] : -1e9f;
            s[st * 4 + 1] = mv.y ? acc[st][1] : -1e9f;
            s[st * 4 + 2] = mv.z ? acc[st][2] : -1e9f;
            s[st * 4 + 3] = mv.w ? acc[st][3] : -1e9f;
        }
        float tmax = s[0];
        #pragma unroll
        for (int j = 1; j < 16; ++j) tmax = fmaxf(tmax, s[j]);
        tmax = fmaxf(tmax, __shfl_xor(tmax, 16));
        tmax = fmaxf(tmax, __shfl_xor(tmax, 32));
        const float mn = fmaxf(m, tmax);
        float ts = 0.f;
        #pragma unroll
        for (int j = 0; j < 16; ++j) ts += __expf(s[j] - mn);
        ts += __shfl_xor(ts, 16);
        ts += __shfl_xor(ts, 32);
        sum = sum * __expf(m - mn) + ts;
        m = mn;
    }
    const float inv = 1.f / sum;

    f32x4 oacc[4];
    #pragma unroll
    for (int mt = 0; mt < 4; ++mt) oacc[mt] = (f32x4){0.f, 0.f, 0.f, 0.f};

    for (int kt = 0; kt < 16; ++kt) {
        const int k0 = kt * 64;
        __syncthreads();
        stageK(k0);
        {
            int d0 = (t & 15) * 4;
            int kl0 = (t >> 4) * 4;
            float4 r[4];
            #pragma unroll
            for (int i = 0; i < 4; ++i)
                r[i] = *(const float4*)(Vh + (size_t)(k0 + kl0 + i) * DH + d0);
            const float* rp = (const float*)r;
            #pragma unroll
            for (int j = 0; j < 4; ++j) {
                unsigned short hv[4], lv[4];
                #pragma unroll
                for (int i = 0; i < 4; ++i) bf_split(rp[i * 4 + j], hv[i], lv[i]);
                int d = d0 + j;
                int csw = kl0 ^ ((d & 7) << 3);
                uint2 uh, ul;
                uh.x = (unsigned int)hv[0] | ((unsigned int)hv[1] << 16);
                uh.y = (unsigned int)hv[2] | ((unsigned int)hv[3] << 16);
                ul.x = (unsigned int)lv[0] | ((unsigned int)lv[1] << 16);
                ul.y = (unsigned int)lv[2] | ((unsigned int)lv[3] << 16);
                *(uint2*)&sVhi[d][csw] = uh;
                *(uint2*)&sVlo[d][csw] = ul;
            }
        }
        __syncthreads();

        #pragma unroll
        for (int st = 0; st < 4; ++st) {
            const int krow = st * 16 + lr;
            const int sw = (krow & 7) << 3;
            f32x4 c = {0.f, 0.f, 0.f, 0.f};
            #pragma unroll
            for (int ds = 0; ds < 2; ++ds) {
                int dc = (ds * 32 + lg * 8) ^ sw;
                short8 ah = *(const short8*)&sKhi[krow][dc];
                short8 al = *(const short8*)&sKlo[krow][dc];
                c = MFMA(ah, qhi[ds], c);
                c = MFMA(ah, qlo[ds], c);
                c = MFMA(al, qhi[ds], c);
            }
            const int4 mv = *(const int4*)(Mw + (size_t)lr * SL + k0 + st * 16 + lg * 4);
            float p0 = mv.x ? __expf(c[0] - m) * inv : 0.f;
            float p1 = mv.y ? __expf(c[1] - m) * inv : 0.f;
            float p2 = mv.z ? __expf(c[2] - m) * inv : 0.f;
            float p3 = mv.w ? __expf(c[3] - m) * inv : 0.f;
            *(float4*)(Pw + (size_t)lr * SL + (k0 + st * 16 + lg * 4)) =
                make_float4(p0, p1, p2, p3);
            unsigned short hv[4], lv[4];
            bf_split(p0, hv[0], lv[0]);
            bf_split(p1, hv[1], lv[1]);
            bf_split(p2, hv[2], lv[2]);
            bf_split(p3, hv[3], lv[3]);
            int col = (st * 16 + lg * 4) ^ ((lr & 7) << 3);
            uint2 uh, ul;
            uh.x = (unsigned int)hv[0] | ((unsigned int)hv[1] << 16);
            uh.y = (unsigned int)hv[2] | ((unsigned int)hv[3] << 16);
            ul.x = (unsigned int)lv[0] | ((unsigned int)lv[1] << 16);
            ul.y = (unsigned int)lv[2] | ((unsigned int)lv[3] << 16);
            *(uint2*)&sPhi[w][lr][col] = uh;
            *(uint2*)&sPlo[w][lr][col] = ul;
        }

        short8 pbh[2], pbl[2];
        #pragma unroll
        for (int ks = 0; ks < 2; ++ks) {
            int col = (ks * 32 + lg * 8) ^ ((lr & 7) << 3);
            pbh[ks] = *(const short8*)&sPhi[w][lr][col];
            pbl[ks] = *(const short8*)&sPlo[w][lr][col];
        }
        #pragma unroll
        for (int mt = 0; mt < 4; ++mt) {
            const int d = mt * 16 + lr;
            const int swd = (d & 7) << 3;
            #pragma unroll
            for (int ks = 0; ks < 2; ++ks) {
                int col = (ks * 32 + lg * 8) ^ swd;
                short8 vh = *(const short8*)&sVhi[d][col];
                short8 vl = *(const short8*)&sVlo[d][col];
                oacc[mt] = MFMA(vh, pbh[ks], oacc[mt]);
                oacc[mt] = MFMA(vh, pbl[ks], oacc[mt]);
                oacc[mt] = MFMA(vl, pbh[ks], oacc[mt]);
            }
        }
    }

    #pragma unroll
    for (int mt = 0; mt < 4; ++mt) {
        float4 o = make_float4(oacc[mt][0], oacc[mt][1], oacc[mt][2], oacc[mt][3]);
        *(float4*)(Ow + (size_t)lr * DH + mt * 16 + lg * 4) = o;
    }
}

extern "C" void kernel_launch(void* const* d_in, const int* in_sizes, int n_in,
                              void* d_out, int out_size, void* d_ws, size_t ws_size,
                              hipStream_t stream) {
    const float* Q = (const float*)d_in[0];
    const float* K = (const float*)d_in[1];
    const float* V = (const float*)d_in[2];
    const int*   M = (const int*)d_in[3];
    float* O = (float*)d_out;
    float* P = O + (size_t)NB * NH * SL * DH;   // outputs: out, p_attn

    const size_t bm_dw = (size_t)NB * SL * BMROW;          // 131072 dwords = 512KB
    const size_t need = bm_dw * 4 + 2 * BLOB_SH * 2;       // 512KB + 32MB
    if (ws_size >= need) {
        unsigned* bmp = (unsigned*)d_ws;
        unsigned short* kbp = (unsigned short*)(bmp + bm_dw);
        unsigned short* vbp = kbp + BLOB_SH;
        hipLaunchKernelGGL(prep_mask, dim3(1024, 1, 1), dim3(NT, 1, 1), 0, stream, M, bmp);
        hipLaunchKernelGGL(prep_split, dim3(NKT, NH, NB), dim3(NT, 1, 1), 0, stream,
                           K, V, kbp, vbp);
        hipLaunchKernelGGL(attn_main, dim3(SL / BQ, NH, NB), dim3(NT, 1, 1), 0, stream,
                           Q, bmp, kbp, vbp, O, P);
    } else {
        hipLaunchKernelGGL(attn_fallback, dim3(SL / BQ, NH, NB), dim3(NT, 1, 1), 0, stream,
                           Q, K, V, M, O, P);
    }
}